// Round 2
// baseline (962.860 us; speedup 1.0000x reference)
//
#include <hip/hip_runtime.h>
#include <hip/hip_bf16.h>
#include <stdint.h>

#define BATCH 8
#define NN 4096
#define DD 64
#define RHH 32

typedef __bf16 bf16x8 __attribute__((ext_vector_type(8)));
typedef float f32x4 __attribute__((ext_vector_type(4)));
typedef float vf4 __attribute__((ext_vector_type(4)));  // native vector for nontemporal builtin

// one v_perm_b32: take high 16 bits of lo -> D[15:0], high 16 of hi -> D[31:16]
__device__ __forceinline__ unsigned pack2(float lo, float hi) {
  return __builtin_amdgcn_perm(__float_as_uint(hi), __float_as_uint(lo), 0x07060302u);
}

// ---------------------------------------------------------------------------
// K0 (1 block): weights-only folding + zero the pooled accumulator.
//   M2f[e][j] = sum_d q2_W[e][d] * Wr2[d][j]   (j<32; cols 32..63 zero)
//   cvec[j]   = qreg_b[j] + sum_d q2_b[d] * Wr2[d][j]
// where Wr2 = qreg_W rows 64..127.
// ---------------------------------------------------------------------------
__global__ __launch_bounds__(256) void k0_fold(
    const float* __restrict__ q2_W, const float* __restrict__ q2_b,
    const float* __restrict__ qreg_W, const float* __restrict__ qreg_b,
    float* __restrict__ M2f, float* __restrict__ cvec,
    float* __restrict__ pooled)
{
  int tid = threadIdx.x;
  // zero pooled accumulators (replaces hipMemsetAsync; k0 precedes kB in-stream)
  for (int i = tid; i < BATCH * DD; i += 256) pooled[i] = 0.f;
  for (int idx = tid; idx < DD * DD; idx += 256) {
    int e = idx >> 6, j = idx & 63;
    float a = 0.f;
    if (j < RHH)
      for (int d = 0; d < DD; ++d) a += q2_W[e * DD + d] * qreg_W[(DD + d) * RHH + j];
    M2f[idx] = a;
  }
  if (tid < RHH) {
    float a = qreg_b[tid];
    for (int d = 0; d < DD; ++d) a += q2_b[d] * qreg_W[(DD + d) * RHH + tid];
    cvec[tid] = a;
  }
}

// ---------------------------------------------------------------------------
// K1: mu0 = relu(xv * mu_1) * m; 2 pre-layers (shfl GEMV);
//     write muT bf16 [B, D, N] (transposed) via LDS.
// ---------------------------------------------------------------------------
__global__ __launch_bounds__(256) void k1_pre(
    const float* __restrict__ xv, const int* __restrict__ mask,
    const float* __restrict__ mu_1, const float* __restrict__ pre_W,
    const float* __restrict__ pre_b, unsigned short* __restrict__ muT)
{
  __shared__ float tile[64][65];
  int b = blockIdx.x >> 6;
  int n0 = (blockIdx.x & 63) << 6;
  int wave = threadIdx.x >> 6, lane = threadIdx.x & 63;
  int nb = n0 + (wave << 4);
  float v[16], acc[16];
  #pragma unroll
  for (int r = 0; r < 16; ++r) {
    int n = nb + r;
    float x  = xv[b * NN + n];
    float mv = (float)mask[b * NN + n];
    v[r] = fmaxf(x * mu_1[lane], 0.f) * mv;
  }
  for (int L = 0; L < 2; ++L) {
    const float* W = pre_W + L * DD * DD;
    float bia = pre_b[L * DD + lane];
    #pragma unroll
    for (int r = 0; r < 16; ++r) acc[r] = bia;
    for (int e = 0; e < 64; ++e) {
      float w = W[e * DD + lane];
      #pragma unroll
      for (int r = 0; r < 16; ++r) acc[r] += __shfl(v[r], e) * w;
    }
    #pragma unroll
    for (int r = 0; r < 16; ++r) v[r] = fmaxf(acc[r], 0.f);
  }
  #pragma unroll
  for (int r = 0; r < 16; ++r) tile[(wave << 4) + r][lane] = v[r];
  __syncthreads();
  int d = threadIdx.x >> 2, ch = (threadIdx.x & 3) << 4;
  unsigned ow[8];
  #pragma unroll
  for (int j = 0; j < 8; ++j)
    ow[j] = pack2(tile[ch + 2 * j][d], tile[ch + 2 * j + 1][d]);
  uint4* dst = (uint4*)(muT + ((size_t)(b * DD + d)) * NN + n0 + ch);
  uint4 o0; o0.x = ow[0]; o0.y = ow[1]; o0.z = ow[2]; o0.w = ow[3];
  uint4 o1; o1.x = ow[4]; o1.y = ow[5]; o1.z = ow[6]; o1.w = ow[7];
  dst[0] = o0; dst[1] = o1;
}

// ---------------------------------------------------------------------------
// KB: fused. Per block: 32 rows, full K=4096.
//   Phase 1: S = A[rows] @ mu  (bf16 MFMA, A packed f32->bf16 via v_perm)
//   Phase 2: LDS transpose C-layout -> lane=d layout
//   Phase 3: *m, 2 post layers, mu2 layer, residual relu -> mu_final (regs)
//   Phase 4: pooled partial (LDS reduce + 64 atomicAdds)
//   Phase 5: t2 = mu_final @ M2f -> write [B,N,32] f32
// grid 1024, block 128 (2 waves x 16 rows).
// XCD swizzle: b = blockIdx & 7  ->  all blocks of batch b live on XCD b
// (round-robin blockIdx->XCD), so each XCD's 4 MiB L2 holds exactly ONE
// 512 KiB muT slice; A loads are nontemporal so the single-use stream
// doesn't evict it.
// ---------------------------------------------------------------------------
__global__ __launch_bounds__(128, 2) void kB_main(
    const float* __restrict__ A, const unsigned short* __restrict__ muT,
    const float* __restrict__ xv, const int* __restrict__ mask,
    const float* __restrict__ mu_1,
    const float* __restrict__ post_W, const float* __restrict__ post_b,
    const float* __restrict__ mu2_W, const float* __restrict__ mu2_b,
    const float* __restrict__ M2f, float* __restrict__ pooled,
    float* __restrict__ t2)
{
  __shared__ float Sc[32][66];
  __shared__ float pools[2][64];
  int b  = blockIdx.x & 7;
  int i0 = (blockIdx.x >> 3) << 5;
  int wave = threadIdx.x >> 6, lane = threadIdx.x & 63;
  int m16 = lane & 15, q = lane >> 4;

  const float* Ap = A + ((size_t)(b * NN + i0 + (wave << 4) + m16)) * NN + q * 8;
  const unsigned short* Bp = muT + ((size_t)(b * DD + m16)) * NN + q * 8;
  f32x4 acc[4] = {{0.f,0.f,0.f,0.f},{0.f,0.f,0.f,0.f},{0.f,0.f,0.f,0.f},{0.f,0.f,0.f,0.f}};
  #pragma unroll 4
  for (int k = 0; k < NN; k += 32) {
    vf4 a0 = __builtin_nontemporal_load((const vf4*)(Ap + k));
    vf4 a1 = __builtin_nontemporal_load((const vf4*)(Ap + k + 4));
    uint4 ap;
    ap.x = pack2(a0.x, a0.y);
    ap.y = pack2(a0.z, a0.w);
    ap.z = pack2(a1.x, a1.y);
    ap.w = pack2(a1.z, a1.w);
    bf16x8 af = __builtin_bit_cast(bf16x8, ap);
    #pragma unroll
    for (int t = 0; t < 4; ++t) {
      uint4 bu = *(const uint4*)(Bp + (size_t)t * 16 * NN + k);
      acc[t] = __builtin_amdgcn_mfma_f32_16x16x32_bf16(
          af, __builtin_bit_cast(bf16x8, bu), acc[t], 0, 0, 0);
    }
  }
  // C-layout: row = q*4+r (within wave's 16), col = t*16+m16
  #pragma unroll
  for (int t = 0; t < 4; ++t)
    #pragma unroll
    for (int r = 0; r < 4; ++r)
      Sc[(wave << 4) + (q << 2) + r][t * 16 + m16] = acc[t][r];
  __syncthreads();

  // lane = d; 16 rows per wave
  int rowg = b * NN + i0 + (wave << 4);
  float v[16], ac[16], mval[16], xvv[16];
  #pragma unroll
  for (int r = 0; r < 16; ++r) {
    mval[r] = (float)mask[rowg + r];
    xvv[r]  = xv[rowg + r];
    v[r] = Sc[(wave << 4) + r][lane] * mval[r];
  }
  for (int L = 0; L < 2; ++L) {
    const float* W = post_W + L * DD * DD;
    float bia = post_b[L * DD + lane];
    #pragma unroll
    for (int r = 0; r < 16; ++r) ac[r] = bia;
    for (int e = 0; e < 64; ++e) {
      float w = W[e * DD + lane];
      #pragma unroll
      for (int r = 0; r < 16; ++r) ac[r] += __shfl(v[r], e) * w;
    }
    #pragma unroll
    for (int r = 0; r < 16; ++r) v[r] = fmaxf(ac[r], 0.f);
  }
  {
    float bia = mu2_b[lane];
    #pragma unroll
    for (int r = 0; r < 16; ++r) ac[r] = bia;
    for (int e = 0; e < 64; ++e) {
      float w = mu2_W[e * DD + lane];
      #pragma unroll
      for (int r = 0; r < 16; ++r) ac[r] += __shfl(v[r], e) * w;
    }
  }
  float mu1c = mu_1[lane];
  float pp = 0.f;
  #pragma unroll
  for (int r = 0; r < 16; ++r) {
    float m1v = fmaxf(xvv[r] * mu1c, 0.f) * mval[r];
    float mu = fmaxf(m1v + ac[r] * mval[r], 0.f);
    v[r] = mu;
    pp += xvv[r] * mu;
  }
  pools[wave][lane] = pp;
  // t2 = mu @ M2f (cols 32..63 of M2f are zero; only lanes<32 store)
  {
    #pragma unroll
    for (int r = 0; r < 16; ++r) ac[r] = 0.f;
    for (int e = 0; e < 64; ++e) {
      float w = M2f[e * DD + lane];
      #pragma unroll
      for (int r = 0; r < 16; ++r) ac[r] += __shfl(v[r], e) * w;
    }
    if (lane < RHH) {
      #pragma unroll
      for (int r = 0; r < 16; ++r)
        t2[(size_t)(rowg + r) * RHH + lane] = ac[r];
    }
  }
  __syncthreads();
  if (threadIdx.x < 64)
    atomicAdd(pooled + b * DD + threadIdx.x,
              pools[0][threadIdx.x] + pools[1][threadIdx.x]);
}

// ---------------------------------------------------------------------------
// KD: per block compute ctot[b] (pooled -> q1 -> @Wr1 + cvec), then
//     q = relu(t2 + ctot) . q_W + q_b, mask -> out.
// grid 512 (b*64 + rowtile64), block 256 (64 rows x 4 lanes).
// ---------------------------------------------------------------------------
__global__ __launch_bounds__(256) void kD_head(
    const float* __restrict__ t2, const float* __restrict__ pooled,
    const float* __restrict__ q1_W, const float* __restrict__ q1_b,
    const float* __restrict__ qreg_W, const float* __restrict__ cvec,
    const float* __restrict__ q_W, const float* __restrict__ q_b,
    const int* __restrict__ mask, float* __restrict__ out)
{
  __shared__ float q1s[64];
  __shared__ float ctot[32];
  __shared__ float qWs[32];
  int b = blockIdx.x >> 6;
  int n0 = (blockIdx.x & 63) << 6;
  int tid = threadIdx.x;
  if (tid < 64) {
    float a = q1_b[tid];
    for (int e = 0; e < 64; ++e) a += pooled[b * DD + e] * q1_W[e * DD + tid];
    q1s[tid] = a;
  }
  __syncthreads();
  if (tid < 32) {
    float a = cvec[tid];
    for (int d = 0; d < 64; ++d) a += q1s[d] * qreg_W[d * RHH + tid];
    ctot[tid] = a;
    qWs[tid] = q_W[tid];
  }
  __syncthreads();
  int row = n0 + (tid >> 2), c0 = (tid & 3) << 3;
  const float* tp = t2 + (size_t)(b * NN + row) * RHH + c0;
  float4 u0 = *(const float4*)tp;
  float4 u1 = *(const float4*)(tp + 4);
  float val = 0.f;
  val += fmaxf(u0.x + ctot[c0 + 0], 0.f) * qWs[c0 + 0];
  val += fmaxf(u0.y + ctot[c0 + 1], 0.f) * qWs[c0 + 1];
  val += fmaxf(u0.z + ctot[c0 + 2], 0.f) * qWs[c0 + 2];
  val += fmaxf(u0.w + ctot[c0 + 3], 0.f) * qWs[c0 + 3];
  val += fmaxf(u1.x + ctot[c0 + 4], 0.f) * qWs[c0 + 4];
  val += fmaxf(u1.y + ctot[c0 + 5], 0.f) * qWs[c0 + 5];
  val += fmaxf(u1.z + ctot[c0 + 6], 0.f) * qWs[c0 + 6];
  val += fmaxf(u1.w + ctot[c0 + 7], 0.f) * qWs[c0 + 7];
  val += __shfl_xor(val, 1);
  val += __shfl_xor(val, 2);
  if ((tid & 3) == 0)
    out[b * NN + row] = (mask[b * NN + row] == 0) ? -99999.0f : (val + q_b[0]);
}

extern "C" void kernel_launch(void* const* d_in, const int* in_sizes, int n_in,
                              void* d_out, int out_size, void* d_ws, size_t ws_size,
                              hipStream_t stream) {
  const float* xv     = (const float*)d_in[0];
  const float* A      = (const float*)d_in[2];
  const int*   mask   = (const int*)d_in[3];
  const float* mu_1   = (const float*)d_in[4];
  const float* mu2_W  = (const float*)d_in[5];
  const float* mu2_b  = (const float*)d_in[6];
  const float* pre_W  = (const float*)d_in[7];
  const float* pre_b  = (const float*)d_in[8];
  const float* post_W = (const float*)d_in[9];
  const float* post_b = (const float*)d_in[10];
  const float* q1_W   = (const float*)d_in[11];
  const float* q1_b   = (const float*)d_in[12];
  const float* q2_W   = (const float*)d_in[13];
  const float* q2_b   = (const float*)d_in[14];
  const float* qreg_W = (const float*)d_in[15];
  const float* qreg_b = (const float*)d_in[16];
  const float* q_W    = (const float*)d_in[17];
  const float* q_b    = (const float*)d_in[18];
  float* out = (float*)d_out;

  char* ws = (char*)d_ws;
  unsigned short* muT  = (unsigned short*)(ws);                       // 4 MB
  float*          t2   = (float*)(ws + ((size_t)4 << 20));            // 4 MB
  float*          pooled = (float*)(ws + ((size_t)8 << 20));          // 2 KB
  float*          M2f  = (float*)(ws + ((size_t)8 << 20) + 4096);     // 16 KB
  float*          cvec = (float*)(ws + ((size_t)8 << 20) + 4096 + 16384); // 128 B

  k0_fold<<<1, 256, 0, stream>>>(q2_W, q2_b, qreg_W, qreg_b, M2f, cvec, pooled);
  k1_pre<<<512, 256, 0, stream>>>(xv, mask, mu_1, pre_W, pre_b, muT);
  kB_main<<<1024, 128, 0, stream>>>(A, muT, xv, mask, mu_1, post_W, post_b,
                                    mu2_W, mu2_b, M2f, pooled, t2);
  kD_head<<<512, 256, 0, stream>>>(t2, pooled, q1_W, q1_b, qreg_W, cvec,
                                   q_W, q_b, mask, out);
}

// Round 3
// 898.713 us; speedup vs baseline: 1.0714x; 1.0714x over previous
//
#include <hip/hip_runtime.h>
#include <hip/hip_bf16.h>
#include <stdint.h>

#define BATCH 8
#define NN 4096
#define DD 64
#define RHH 32

typedef __bf16 bf16x8 __attribute__((ext_vector_type(8)));
typedef float f32x4 __attribute__((ext_vector_type(4)));
typedef float vf4 __attribute__((ext_vector_type(4)));  // native vector for nontemporal builtin

// one v_perm_b32: take high 16 bits of lo -> D[15:0], high 16 of hi -> D[31:16]
__device__ __forceinline__ unsigned pack2(float lo, float hi) {
  return __builtin_amdgcn_perm(__float_as_uint(hi), __float_as_uint(lo), 0x07060302u);
}

// ---------------------------------------------------------------------------
// KP (grid 9): blocks 0..7 = per-batch active-row compaction (wave ballot);
//              block 8     = weight folding (old k0) + pooled zero.
//   rowidx[b][k] = k-th active row index (mask!=0), rowcnt[b] = count.
//   M2f[e][j] = sum_d q2_W[e][d] * qreg_W[64+d][j]  (j<32; cols 32..63 zero)
//   cvec[j]   = qreg_b[j] + sum_d q2_b[d] * qreg_W[64+d][j]
// ---------------------------------------------------------------------------
__global__ __launch_bounds__(256) void kP_prep(
    const int* __restrict__ mask,
    const float* __restrict__ q2_W, const float* __restrict__ q2_b,
    const float* __restrict__ qreg_W, const float* __restrict__ qreg_b,
    float* __restrict__ M2f, float* __restrict__ cvec,
    float* __restrict__ pooled,
    int* __restrict__ rowidx, int* __restrict__ rowcnt)
{
  int blk = blockIdx.x;
  if (blk < BATCH) {
    if (threadIdx.x >= 64) return;           // wave 0 only
    int lane = threadIdx.x;
    int base = 0;
    for (int c = 0; c < NN; c += 64) {
      int n = c + lane;
      bool act = (mask[blk * NN + n] != 0);
      unsigned long long bal = __ballot(act);
      int pre = __popcll(bal & ((1ull << lane) - 1ull));
      if (act) rowidx[blk * NN + base + pre] = n;
      base += __popcll(bal);
    }
    if (lane == 0) rowcnt[blk] = base;
  } else {
    int tid = threadIdx.x;
    for (int i = tid; i < BATCH * DD; i += 256) pooled[i] = 0.f;
    for (int idx = tid; idx < DD * DD; idx += 256) {
      int e = idx >> 6, j = idx & 63;
      float a = 0.f;
      if (j < RHH)
        for (int d = 0; d < DD; ++d) a += q2_W[e * DD + d] * qreg_W[(DD + d) * RHH + j];
      M2f[idx] = a;
    }
    if (tid < RHH) {
      float a = qreg_b[tid];
      for (int d = 0; d < DD; ++d) a += q2_b[d] * qreg_W[(DD + d) * RHH + tid];
      cvec[tid] = a;
    }
  }
}

// ---------------------------------------------------------------------------
// K1: mu0 = relu(xv * mu_1) * m; 2 pre-layers (shfl GEMV);
//     write muT bf16 [B, D, N] (transposed) via LDS.
//     (ALL rows needed here: masked rows carry pre-layer bias values that
//      feed S as K-columns... those are zeroed by m BEFORE the pre layers,
//      so muT[masked n] = pre(0) = bias-driven values -- exactly what the
//      reference computes. Unchanged from prior round.)
// ---------------------------------------------------------------------------
__global__ __launch_bounds__(256) void k1_pre(
    const float* __restrict__ xv, const int* __restrict__ mask,
    const float* __restrict__ mu_1, const float* __restrict__ pre_W,
    const float* __restrict__ pre_b, unsigned short* __restrict__ muT)
{
  __shared__ float tile[64][65];
  int b = blockIdx.x >> 6;
  int n0 = (blockIdx.x & 63) << 6;
  int wave = threadIdx.x >> 6, lane = threadIdx.x & 63;
  int nb = n0 + (wave << 4);
  float v[16], acc[16];
  #pragma unroll
  for (int r = 0; r < 16; ++r) {
    int n = nb + r;
    float x  = xv[b * NN + n];
    float mv = (float)mask[b * NN + n];
    v[r] = fmaxf(x * mu_1[lane], 0.f) * mv;
  }
  for (int L = 0; L < 2; ++L) {
    const float* W = pre_W + L * DD * DD;
    float bia = pre_b[L * DD + lane];
    #pragma unroll
    for (int r = 0; r < 16; ++r) acc[r] = bia;
    for (int e = 0; e < 64; ++e) {
      float w = W[e * DD + lane];
      #pragma unroll
      for (int r = 0; r < 16; ++r) acc[r] += __shfl(v[r], e) * w;
    }
    #pragma unroll
    for (int r = 0; r < 16; ++r) v[r] = fmaxf(acc[r], 0.f);
  }
  #pragma unroll
  for (int r = 0; r < 16; ++r) tile[(wave << 4) + r][lane] = v[r];
  __syncthreads();
  int d = threadIdx.x >> 2, ch = (threadIdx.x & 3) << 4;
  unsigned ow[8];
  #pragma unroll
  for (int j = 0; j < 8; ++j)
    ow[j] = pack2(tile[ch + 2 * j][d], tile[ch + 2 * j + 1][d]);
  uint4* dst = (uint4*)(muT + ((size_t)(b * DD + d)) * NN + n0 + ch);
  uint4 o0; o0.x = ow[0]; o0.y = ow[1]; o0.z = ow[2]; o0.w = ow[3];
  uint4 o1; o1.x = ow[4]; o1.y = ow[5]; o1.z = ow[6]; o1.w = ow[7];
  dst[0] = o0; dst[1] = o1;
}

// ---------------------------------------------------------------------------
// KB: fused main. Per block: up to 32 ACTIVE rows (compacted), full K=4096.
//   Masked rows are provably zero in the final mu (m zeroes mu_pool before
//   post layers and mu_2 after mu2_W), contribute nothing to pooled, and
//   their outputs are replaced by -99999 -- so we skip their A rows
//   entirely: ~50% less A traffic (the dominant HBM stream).
//   Tail slots (beyond rowcnt) alias row lidx[0] for the MFMA and are
//   masked out of pooled / t2 stores.
// grid 1024 (b = blockIdx&7 for XCD-L2 batch affinity), block 128.
// ---------------------------------------------------------------------------
__global__ __launch_bounds__(128, 2) void kB_main(
    const float* __restrict__ A, const unsigned short* __restrict__ muT,
    const float* __restrict__ xv, const float* __restrict__ mu_1,
    const float* __restrict__ post_W, const float* __restrict__ post_b,
    const float* __restrict__ mu2_W, const float* __restrict__ mu2_b,
    const float* __restrict__ M2f, float* __restrict__ pooled,
    float* __restrict__ t2,
    const int* __restrict__ rowidx, const int* __restrict__ rowcnt)
{
  __shared__ float Sc[32][66];
  __shared__ float pools[2][64];
  __shared__ int lidx[32];
  int b    = blockIdx.x & 7;
  int tile = blockIdx.x >> 3;
  int cnt  = rowcnt[b];
  int i0   = tile << 5;
  if (i0 >= cnt) return;                 // block-uniform early exit
  if (threadIdx.x < 32) {
    int t = i0 + threadIdx.x;
    lidx[threadIdx.x] = (t < cnt) ? rowidx[b * NN + t] : -1;
  }
  __syncthreads();

  int wave = threadIdx.x >> 6, lane = threadIdx.x & 63;
  int m16 = lane & 15, q = lane >> 4;

  int ridx = lidx[(wave << 4) + m16];
  int rA = (ridx < 0) ? lidx[0] : ridx;  // lidx[0] valid since i0 < cnt
  const float* Ap = A + ((size_t)(b * NN + rA)) * NN + q * 8;
  const unsigned short* Bp = muT + ((size_t)(b * DD + m16)) * NN + q * 8;
  f32x4 acc[4] = {{0.f,0.f,0.f,0.f},{0.f,0.f,0.f,0.f},{0.f,0.f,0.f,0.f},{0.f,0.f,0.f,0.f}};
  #pragma unroll 4
  for (int k = 0; k < NN; k += 32) {
    vf4 a0 = __builtin_nontemporal_load((const vf4*)(Ap + k));
    vf4 a1 = __builtin_nontemporal_load((const vf4*)(Ap + k + 4));
    uint4 ap;
    ap.x = pack2(a0.x, a0.y);
    ap.y = pack2(a0.z, a0.w);
    ap.z = pack2(a1.x, a1.y);
    ap.w = pack2(a1.z, a1.w);
    bf16x8 af = __builtin_bit_cast(bf16x8, ap);
    #pragma unroll
    for (int t = 0; t < 4; ++t) {
      uint4 bu = *(const uint4*)(Bp + (size_t)t * 16 * NN + k);
      acc[t] = __builtin_amdgcn_mfma_f32_16x16x32_bf16(
          af, __builtin_bit_cast(bf16x8, bu), acc[t], 0, 0, 0);
    }
  }
  // C-layout: row = q*4+r (within wave's 16), col = t*16+m16
  #pragma unroll
  for (int t = 0; t < 4; ++t)
    #pragma unroll
    for (int r = 0; r < 4; ++r)
      Sc[(wave << 4) + (q << 2) + r][t * 16 + m16] = acc[t][r];
  __syncthreads();

  // lane = d; 16 (compacted) rows per wave; all active rows have mask==1
  int base_b = b * NN;
  float v[16], ac[16], xvv[16];
  #pragma unroll
  for (int r = 0; r < 16; ++r) {
    int g = lidx[(wave << 4) + r];
    xvv[r] = (g >= 0) ? xv[base_b + g] : 0.f;
    v[r] = Sc[(wave << 4) + r][lane];
  }
  for (int L = 0; L < 2; ++L) {
    const float* W = post_W + L * DD * DD;
    float bia = post_b[L * DD + lane];
    #pragma unroll
    for (int r = 0; r < 16; ++r) ac[r] = bia;
    for (int e = 0; e < 64; ++e) {
      float w = W[e * DD + lane];
      #pragma unroll
      for (int r = 0; r < 16; ++r) ac[r] += __shfl(v[r], e) * w;
    }
    #pragma unroll
    for (int r = 0; r < 16; ++r) v[r] = fmaxf(ac[r], 0.f);
  }
  {
    float bia = mu2_b[lane];
    #pragma unroll
    for (int r = 0; r < 16; ++r) ac[r] = bia;
    for (int e = 0; e < 64; ++e) {
      float w = mu2_W[e * DD + lane];
      #pragma unroll
      for (int r = 0; r < 16; ++r) ac[r] += __shfl(v[r], e) * w;
    }
  }
  float mu1c = mu_1[lane];
  float pp = 0.f;
  #pragma unroll
  for (int r = 0; r < 16; ++r) {
    float m1v = fmaxf(xvv[r] * mu1c, 0.f);       // xvv==0 for invalid slots
    float mu = fmaxf(m1v + ac[r], 0.f);
    v[r] = mu;
    pp += xvv[r] * mu;                           // invalid slots add 0
  }
  pools[wave][lane] = pp;
  // t2 = mu @ M2f (cols 32..63 of M2f are zero; only lanes<32 store)
  {
    #pragma unroll
    for (int r = 0; r < 16; ++r) ac[r] = 0.f;
    for (int e = 0; e < 64; ++e) {
      float w = M2f[e * DD + lane];
      #pragma unroll
      for (int r = 0; r < 16; ++r) ac[r] += __shfl(v[r], e) * w;
    }
    if (lane < RHH) {
      #pragma unroll
      for (int r = 0; r < 16; ++r) {
        int g = lidx[(wave << 4) + r];
        if (g >= 0)
          t2[(size_t)(base_b + g) * RHH + lane] = ac[r];
      }
    }
  }
  __syncthreads();
  if (threadIdx.x < 64)
    atomicAdd(pooled + b * DD + threadIdx.x,
              pools[0][threadIdx.x] + pools[1][threadIdx.x]);
}

// ---------------------------------------------------------------------------
// KD: per block compute ctot[b] (pooled -> q1 -> @Wr1 + cvec), then
//     q = relu(t2 + ctot) . q_W + q_b, mask -> out.
//     Masked rows read un-written (poisoned) t2 but the 4-lane reduction
//     never crosses rows and the result is replaced by -99999.
// grid 512 (b*64 + rowtile64), block 256 (64 rows x 4 lanes).
// ---------------------------------------------------------------------------
__global__ __launch_bounds__(256) void kD_head(
    const float* __restrict__ t2, const float* __restrict__ pooled,
    const float* __restrict__ q1_W, const float* __restrict__ q1_b,
    const float* __restrict__ qreg_W, const float* __restrict__ cvec,
    const float* __restrict__ q_W, const float* __restrict__ q_b,
    const int* __restrict__ mask, float* __restrict__ out)
{
  __shared__ float q1s[64];
  __shared__ float ctot[32];
  __shared__ float qWs[32];
  int b = blockIdx.x >> 6;
  int n0 = (blockIdx.x & 63) << 6;
  int tid = threadIdx.x;
  if (tid < 64) {
    float a = q1_b[tid];
    for (int e = 0; e < 64; ++e) a += pooled[b * DD + e] * q1_W[e * DD + tid];
    q1s[tid] = a;
  }
  __syncthreads();
  if (tid < 32) {
    float a = cvec[tid];
    for (int d = 0; d < 64; ++d) a += q1s[d] * qreg_W[d * RHH + tid];
    ctot[tid] = a;
    qWs[tid] = q_W[tid];
  }
  __syncthreads();
  int row = n0 + (tid >> 2), c0 = (tid & 3) << 3;
  const float* tp = t2 + (size_t)(b * NN + row) * RHH + c0;
  float4 u0 = *(const float4*)tp;
  float4 u1 = *(const float4*)(tp + 4);
  float val = 0.f;
  val += fmaxf(u0.x + ctot[c0 + 0], 0.f) * qWs[c0 + 0];
  val += fmaxf(u0.y + ctot[c0 + 1], 0.f) * qWs[c0 + 1];
  val += fmaxf(u0.z + ctot[c0 + 2], 0.f) * qWs[c0 + 2];
  val += fmaxf(u0.w + ctot[c0 + 3], 0.f) * qWs[c0 + 3];
  val += fmaxf(u1.x + ctot[c0 + 4], 0.f) * qWs[c0 + 4];
  val += fmaxf(u1.y + ctot[c0 + 5], 0.f) * qWs[c0 + 5];
  val += fmaxf(u1.z + ctot[c0 + 6], 0.f) * qWs[c0 + 6];
  val += fmaxf(u1.w + ctot[c0 + 7], 0.f) * qWs[c0 + 7];
  val += __shfl_xor(val, 1);
  val += __shfl_xor(val, 2);
  if ((tid & 3) == 0)
    out[b * NN + row] = (mask[b * NN + row] == 0) ? -99999.0f : (val + q_b[0]);
}

extern "C" void kernel_launch(void* const* d_in, const int* in_sizes, int n_in,
                              void* d_out, int out_size, void* d_ws, size_t ws_size,
                              hipStream_t stream) {
  const float* xv     = (const float*)d_in[0];
  const float* A      = (const float*)d_in[2];
  const int*   mask   = (const int*)d_in[3];
  const float* mu_1   = (const float*)d_in[4];
  const float* mu2_W  = (const float*)d_in[5];
  const float* mu2_b  = (const float*)d_in[6];
  const float* pre_W  = (const float*)d_in[7];
  const float* pre_b  = (const float*)d_in[8];
  const float* post_W = (const float*)d_in[9];
  const float* post_b = (const float*)d_in[10];
  const float* q1_W   = (const float*)d_in[11];
  const float* q1_b   = (const float*)d_in[12];
  const float* q2_W   = (const float*)d_in[13];
  const float* q2_b   = (const float*)d_in[14];
  const float* qreg_W = (const float*)d_in[15];
  const float* qreg_b = (const float*)d_in[16];
  const float* q_W    = (const float*)d_in[17];
  const float* q_b    = (const float*)d_in[18];
  float* out = (float*)d_out;

  char* ws = (char*)d_ws;
  unsigned short* muT    = (unsigned short*)(ws);                           // 4 MB
  float*          t2     = (float*)(ws + ((size_t)4 << 20));                // 4 MB
  float*          pooled = (float*)(ws + ((size_t)8 << 20));                // 2 KB
  float*          M2f    = (float*)(ws + ((size_t)8 << 20) + 4096);         // 16 KB
  float*          cvec   = (float*)(ws + ((size_t)8 << 20) + 4096 + 16384); // 128 B
  int*            rowidx = (int*)(ws + ((size_t)9 << 20));                  // 128 KB
  int*            rowcnt = (int*)(ws + ((size_t)9 << 20) + (128 << 10));    // 32 B

  kP_prep<<<BATCH + 1, 256, 0, stream>>>(mask, q2_W, q2_b, qreg_W, qreg_b,
                                         M2f, cvec, pooled, rowidx, rowcnt);
  k1_pre<<<512, 256, 0, stream>>>(xv, mask, mu_1, pre_W, pre_b, muT);
  kB_main<<<1024, 128, 0, stream>>>(A, muT, xv, mu_1, post_W, post_b,
                                    mu2_W, mu2_b, M2f, pooled, t2,
                                    rowidx, rowcnt);
  kD_head<<<512, 256, 0, stream>>>(t2, pooled, q1_W, q1_b, qreg_W, cvec,
                                   q_W, q_b, mask, out);
}